// Round 9
// baseline (2533.046 us; speedup 1.0000x reference)
//
#include <hip/hip_runtime.h>
#include <cstdint>

// ===================== GCN encoder on MI355X =====================
// out = gcn(relu(gcn(x, W1, b1)), W2, b2)
// gcn(x,W,b)[i] = dinv[i] * ( sum_{e: dst=i} (xW*dinv)[src] + (xW*dinv)[i] ) + b
// dinv = rsqrt(indeg+1) (self-loop), identical for both layers.
//
// R15: delete the CSR sort. Aggregates now run block-per-bucket (64 nodes,
// BSHIFT 6) over the bucket-grouped (unsorted) `packed` edges, accumulating
// into an LDS fp32 acc[64 dims][65] via ds_add_f32 atomics:
//  - bcsr (full within-bucket counting sort, ~read E + sort + write E)
//    REMOVED; rowptr/csr buffers gone.
//  - tiny bdeg kernel (read packed, LDS deg, write dinv) provides dinv
//    before gemm1. scanbucket returns (nb=1563 > in-block scan width).
//  - per-node degree-tail divergence gone: block work = bucket size
//    (uniform +-2%); edge reads perfectly coalesced.
//  - agg1 epilogue = fused gemm2 as a standard full 64-row MFMA tile
//    (H[64][64]bf16 @ W2) -> *dinv -> bufB. agg2 -> fp32 out.
// LDS-atomic ordering only reassociates fp32 sums (noise << bf16 quant).
// hist/scancol/bscatter unchanged except BSHIFT 6 sizing.

#define BSHIFT 6          // 64 nodes per bucket
#define NBMAX 1568        // >= ceil(100000/64) = 1563
#define CH 8192           // edges per block in passes A/C

typedef __attribute__((ext_vector_type(8))) short bf16x8;
typedef __attribute__((ext_vector_type(4))) float f32x4;

// ---------------- bf16 helpers ----------------
__device__ inline unsigned short f2bf(float f) {
    unsigned u = __float_as_uint(f);
    unsigned r = (u + 0x7FFFu + ((u >> 16) & 1u)) >> 16;  // RNE
    return (unsigned short)r;
}
__device__ inline unsigned pack2(float a, float b) {
    return (unsigned)f2bf(a) | ((unsigned)f2bf(b) << 16);
}
__device__ inline float blo(unsigned u) { return __uint_as_float(u << 16); }
__device__ inline float bhi(unsigned u) { return __uint_as_float(u & 0xFFFF0000u); }

// ---------------- pass A: bucket histogram (+ folded weight prep) ----------
__global__ __launch_bounds__(256) void hist_kernel(const int* __restrict__ dst,
                                                   int* __restrict__ histmat,
                                                   int E, int nb, int nblk,
                                                   const float* __restrict__ W1,
                                                   const float* __restrict__ W2,
                                                   unsigned short* __restrict__ W1t,
                                                   unsigned short* __restrict__ W2t) {
    if (blockIdx.x >= (unsigned)nblk) {
        // weight-prep blocks: W[K][64] fp32 -> Wt[64][K] bf16
        int i = (blockIdx.x - nblk) * 256 + threadIdx.x;
        if (i < 128 * 64) {
            int k = i >> 6, n = i & 63;
            W1t[n * 128 + k] = f2bf(W1[i]);
        }
        int j = i - 128 * 64;
        if (j >= 0 && j < 64 * 64) {
            int k = j >> 6, n = j & 63;
            W2t[n * 64 + k] = f2bf(W2[j]);
        }
        return;
    }
    __shared__ int hist[NBMAX];
    int t = threadIdx.x;
    for (int b = t; b < nb; b += 256) hist[b] = 0;
    __syncthreads();
    int base = blockIdx.x * CH;
#pragma unroll
    for (int j = 0; j < CH / 1024; ++j) {
        int idx = base + j * 1024 + t * 4;
        if (idx + 4 <= E) {
            int4 d = *(const int4*)(dst + idx);
            atomicAdd(&hist[d.x >> BSHIFT], 1);
            atomicAdd(&hist[d.y >> BSHIFT], 1);
            atomicAdd(&hist[d.z >> BSHIFT], 1);
            atomicAdd(&hist[d.w >> BSHIFT], 1);
        } else {
            for (int k = 0; k < 4; ++k)
                if (idx + k < E) atomicAdd(&hist[dst[idx + k] >> BSHIFT], 1);
        }
    }
    __syncthreads();
    for (int b = t; b < nb; b += 256) histmat[blockIdx.x * nb + b] = hist[b];
}

// ---------------- pass B1: per-bucket scan over blocks (nblk <= 1024) -------
__global__ __launch_bounds__(256) void scancol_kernel(const int* __restrict__ histmat,
                                                      int* __restrict__ colbase,
                                                      int* __restrict__ buckettotal,
                                                      int nb, int nblk) {
    __shared__ int ts[256];
    int b = blockIdx.x;
    int t = threadIdx.x;
    int v[4];
    int tsum = 0;
#pragma unroll
    for (int k = 0; k < 4; ++k) {
        int blk = t * 4 + k;
        v[k] = (blk < nblk) ? histmat[blk * nb + b] : 0;
        tsum += v[k];
    }
    ts[t] = tsum;
    __syncthreads();
    for (int ofs = 1; ofs < 256; ofs <<= 1) {
        int val = (t >= ofs) ? ts[t - ofs] : 0;
        __syncthreads();
        ts[t] += val;
        __syncthreads();
    }
    int run = ts[t] - tsum;
#pragma unroll
    for (int k = 0; k < 4; ++k) {
        int blk = t * 4 + k;
        if (blk < nblk) colbase[blk * nb + b] = run;
        run += v[k];
    }
    if (t == 255) buckettotal[b] = ts[255];
}

// ---------------- pass B2: scan bucket totals (single block, 8/thread) ------
__global__ __launch_bounds__(256) void scanbucket_kernel(const int* __restrict__ buckettotal,
                                                         int* __restrict__ bucketbase,
                                                         int nb, int E) {
    __shared__ int ts[256];
    int t = threadIdx.x;
    int v[8];
    int tsum = 0;
#pragma unroll
    for (int k = 0; k < 8; ++k) {
        int b = t * 8 + k;
        v[k] = (b < nb) ? buckettotal[b] : 0;
        tsum += v[k];
    }
    ts[t] = tsum;
    __syncthreads();
    for (int ofs = 1; ofs < 256; ofs <<= 1) {
        int val = (t >= ofs) ? ts[t - ofs] : 0;
        __syncthreads();
        ts[t] += val;
        __syncthreads();
    }
    int run = ts[t] - tsum;
#pragma unroll
    for (int k = 0; k < 8; ++k) {
        int b = t * 8 + k;
        if (b < nb) bucketbase[b] = run;
        run += v[k];
    }
    if (t == 0) bucketbase[nb] = E;
}

// ---------------- pass C: scatter into bucket regions (LDS cursors) ---------
__global__ __launch_bounds__(256) void bscatter_kernel(const int* __restrict__ src,
                                                       const int* __restrict__ dst,
                                                       const int* __restrict__ colbase,
                                                       const int* __restrict__ bucketbase,
                                                       int* __restrict__ packed,
                                                       int E, int nb) {
    __shared__ int cur[NBMAX];
    int t = threadIdx.x;
    for (int b = t; b < nb; b += 256)
        cur[b] = bucketbase[b] + colbase[(size_t)blockIdx.x * nb + b];
    __syncthreads();
    int base = blockIdx.x * CH;
#pragma unroll
    for (int j = 0; j < CH / 1024; ++j) {
        int idx = base + j * 1024 + t * 4;
        if (idx + 4 <= E) {
            int4 d = *(const int4*)(dst + idx);
            int4 s = *(const int4*)(src + idx);
            int p;
            p = atomicAdd(&cur[d.x >> BSHIFT], 1); packed[p] = ((d.x & 63) << 17) | s.x;
            p = atomicAdd(&cur[d.y >> BSHIFT], 1); packed[p] = ((d.y & 63) << 17) | s.y;
            p = atomicAdd(&cur[d.z >> BSHIFT], 1); packed[p] = ((d.z & 63) << 17) | s.z;
            p = atomicAdd(&cur[d.w >> BSHIFT], 1); packed[p] = ((d.w & 63) << 17) | s.w;
        } else {
            for (int k = 0; k < 4; ++k)
                if (idx + k < E) {
                    int dd = dst[idx + k], ss = src[idx + k];
                    int p = atomicAdd(&cur[dd >> BSHIFT], 1);
                    packed[p] = ((dd & 63) << 17) | ss;
                }
        }
    }
}

// ---------------- pass D: per-bucket degree -> dinv (no sort) ---------------
__global__ __launch_bounds__(256) void bdeg_kernel(const int* __restrict__ packed,
                                                   const int* __restrict__ bucketbase,
                                                   float* __restrict__ dinv, int N) {
    __shared__ int deg[64];
    int t = threadIdx.x;
    int b = blockIdx.x;
    if (t < 64) deg[t] = 0;
    __syncthreads();
    int bb0 = bucketbase[b], bb1 = bucketbase[b + 1];
    for (int i = bb0 + t; i < bb1; i += 256)
        atomicAdd(&deg[packed[i] >> 17], 1);
    __syncthreads();
    int node0 = b << BSHIFT;
    if (t < 64 && node0 + t < N)
        dinv[node0 + t] = rsqrtf((float)(deg[t] + 1));
}

// ------- MFMA GEMM1: bufA[M,64]bf16 = (X[M,128]f32 @ W1[128,64]) * dinv ----
__global__ __launch_bounds__(256) void gemm1_kernel(const float* __restrict__ X,
                                                    const unsigned short* __restrict__ Wt,
                                                    const float* __restrict__ dinv,
                                                    unsigned short* __restrict__ Ybf, int M) {
    constexpr int K = 128, KP = 136;
    __shared__ unsigned short Xs[64 * KP];   // reused as Cs (64*72) in epilogue
    __shared__ unsigned short Ws[64 * KP];
    int t = threadIdx.x;
    int row0 = blockIdx.x * 64;

    for (int i = t; i < 64 * K / 8; i += 256) {
        int r = i / (K / 8), c8 = i % (K / 8);
        *(uint4*)(&Ws[r * KP + c8 * 8]) = ((const uint4*)Wt)[i];
    }
    for (int i = t; i < 64 * K / 4; i += 256) {
        int r = i / (K / 4), c4 = i % (K / 4);
        int gr = row0 + r;
        float4 v = make_float4(0.f, 0.f, 0.f, 0.f);
        if (gr < M) v = ((const float4*)(X + (size_t)gr * K))[c4];
        uint2 p;
        p.x = pack2(v.x, v.y);
        p.y = pack2(v.z, v.w);
        *(uint2*)(&Xs[r * KP + c4 * 4]) = p;
    }
    __syncthreads();

    int lane = t & 63;
    int w = t >> 6;
    int m = lane & 15;
    int q = lane >> 4;

    f32x4 acc[4];
#pragma unroll
    for (int nt = 0; nt < 4; ++nt) acc[nt] = (f32x4){0.f, 0.f, 0.f, 0.f};

#pragma unroll
    for (int s = 0; s < K / 32; ++s) {
        bf16x8 a = *(const bf16x8*)(&Xs[(16 * w + m) * KP + s * 32 + q * 8]);
#pragma unroll
        for (int nt = 0; nt < 4; ++nt) {
            bf16x8 b = *(const bf16x8*)(&Ws[(16 * nt + m) * KP + s * 32 + q * 8]);
            acc[nt] = __builtin_amdgcn_mfma_f32_16x16x32_bf16(a, b, acc[nt], 0, 0, 0);
        }
    }
    __syncthreads();

    unsigned short* Cs = Xs;
#pragma unroll
    for (int nt = 0; nt < 4; ++nt)
#pragma unroll
        for (int r = 0; r < 4; ++r) {
            int row = 16 * w + q * 4 + r;
            int gr = row0 + row;
            float d = (gr < M) ? dinv[gr] : 0.f;
            Cs[row * 72 + nt * 16 + m] = f2bf(acc[nt][r] * d);
        }
    __syncthreads();
    for (int i = t; i < 64 * 64 / 8; i += 256) {
        int r = i >> 3, c8 = i & 7;
        int gr = row0 + r;
        if (gr < M)
            *(uint4*)(Ybf + (size_t)gr * 64 + c8 * 8) = *(const uint4*)(&Cs[r * 72 + c8 * 8]);
    }
}

// ---------------- bucket aggregation (LDS fp32 atomic accumulate) -----------
// acc layout [dim][node]: addr = dim*65 + d  (65 = 64+1 pad; 65 mod 32 = 1
// -> bank = (dim + d) mod 32: random d spreads banks; 2-way is free).
#define ACCADD(dd, v)                                          \
    atomicAdd(&acc[(sub * 8 + 0) * 65 + (dd)], blo(v.x));      \
    atomicAdd(&acc[(sub * 8 + 1) * 65 + (dd)], bhi(v.x));      \
    atomicAdd(&acc[(sub * 8 + 2) * 65 + (dd)], blo(v.y));      \
    atomicAdd(&acc[(sub * 8 + 3) * 65 + (dd)], bhi(v.y));      \
    atomicAdd(&acc[(sub * 8 + 4) * 65 + (dd)], blo(v.z));      \
    atomicAdd(&acc[(sub * 8 + 5) * 65 + (dd)], bhi(v.z));      \
    atomicAdd(&acc[(sub * 8 + 6) * 65 + (dd)], blo(v.w));      \
    atomicAdd(&acc[(sub * 8 + 7) * 65 + (dd)], bhi(v.w));

// DO_GEMM=true (layer 1): H = relu(acc*dinv+b1) -> bf16 -> @W2 -> *dinv -> bufB
// DO_GEMM=false (layer 2): out = acc*dinv + b2 -> fp32
template <bool DO_GEMM>
__global__ __launch_bounds__(256) void agg_bucket_kernel(
        const unsigned* __restrict__ hsu, const int* __restrict__ packed,
        const int* __restrict__ bucketbase, const float* __restrict__ dinv,
        const float* __restrict__ bias, const unsigned short* __restrict__ W2t,
        void* __restrict__ outv, int N) {
    __shared__ __align__(16) float acc[64 * 65];              // 16640 B
    __shared__ unsigned short W2s[DO_GEMM ? 64 * 72 : 8];     // 9216 B
    __shared__ unsigned short Hs[DO_GEMM ? 64 * 72 : 8];      // 9216 B
    int t = threadIdx.x;
    int b = blockIdx.x;
    int node0 = b << BSHIFT;
    int nlocal = min(64, N - node0);
    int sub = t & 7;

    if (DO_GEMM) {
        for (int i = t; i < 64 * 64 / 8; i += 256) {
            int r = i >> 3, c8 = i & 7;
            *(uint4*)(&W2s[r * 72 + c8 * 8]) = ((const uint4*)W2t)[i];
        }
    }
    // init acc with self-loop message (0 for out-of-range rows)
    for (int i = t; i < 64 * 8; i += 256) {
        int d = i >> 3, s2 = i & 7;
        uint4 v = make_uint4(0u, 0u, 0u, 0u);
        if (d < nlocal) v = *(const uint4*)(hsu + (size_t)(node0 + d) * 32 + s2 * 4);
        acc[(s2 * 8 + 0) * 65 + d] = blo(v.x); acc[(s2 * 8 + 1) * 65 + d] = bhi(v.x);
        acc[(s2 * 8 + 2) * 65 + d] = blo(v.y); acc[(s2 * 8 + 3) * 65 + d] = bhi(v.y);
        acc[(s2 * 8 + 4) * 65 + d] = blo(v.z); acc[(s2 * 8 + 5) * 65 + d] = bhi(v.z);
        acc[(s2 * 8 + 6) * 65 + d] = blo(v.w); acc[(s2 * 8 + 7) * 65 + d] = bhi(v.w);
    }
    __syncthreads();

    int bb0 = bucketbase[b], bb1 = bucketbase[b + 1];
    int cnt = bb1 - bb0;
    int gbase = t & 56;   // 8-lane group base within wave

    // main loop: 256 edges/batch; each 8-lane group handles 8 edges
    int cmain = cnt & ~255;
    for (int base = 0; base < cmain; base += 256) {
        int myedge = packed[bb0 + base + t];   // coalesced
        int e0 = __shfl(myedge, gbase + 0, 64);
        int e1 = __shfl(myedge, gbase + 1, 64);
        int e2 = __shfl(myedge, gbase + 2, 64);
        int e3 = __shfl(myedge, gbase + 3, 64);
        int e4 = __shfl(myedge, gbase + 4, 64);
        int e5 = __shfl(myedge, gbase + 5, 64);
        int e6 = __shfl(myedge, gbase + 6, 64);
        int e7 = __shfl(myedge, gbase + 7, 64);
        uint4 v0 = *(const uint4*)(hsu + (size_t)(e0 & 0x1FFFF) * 32 + sub * 4);
        uint4 v1 = *(const uint4*)(hsu + (size_t)(e1 & 0x1FFFF) * 32 + sub * 4);
        uint4 v2 = *(const uint4*)(hsu + (size_t)(e2 & 0x1FFFF) * 32 + sub * 4);
        uint4 v3 = *(const uint4*)(hsu + (size_t)(e3 & 0x1FFFF) * 32 + sub * 4);
        uint4 v4 = *(const uint4*)(hsu + (size_t)(e4 & 0x1FFFF) * 32 + sub * 4);
        uint4 v5 = *(const uint4*)(hsu + (size_t)(e5 & 0x1FFFF) * 32 + sub * 4);
        uint4 v6 = *(const uint4*)(hsu + (size_t)(e6 & 0x1FFFF) * 32 + sub * 4);
        uint4 v7 = *(const uint4*)(hsu + (size_t)(e7 & 0x1FFFF) * 32 + sub * 4);
        int d0 = e0 >> 17, d1 = e1 >> 17, d2 = e2 >> 17, d3 = e3 >> 17;
        int d4 = e4 >> 17, d5 = e5 >> 17, d6 = e6 >> 17, d7 = e7 >> 17;
        ACCADD(d0, v0); ACCADD(d1, v1); ACCADD(d2, v2); ACCADD(d3, v3);
        ACCADD(d4, v4); ACCADD(d5, v5); ACCADD(d6, v6); ACCADD(d7, v7);
    }
    // tail: one edge per group per pass (all 8 lanes load same word)
    for (int i = cmain + (t >> 3); i < cnt; i += 32) {
        int v = packed[bb0 + i];
        int dd = v >> 17;
        uint4 x = *(const uint4*)(hsu + (size_t)(v & 0x1FFFF) * 32 + sub * 4);
        ACCADD(dd, x);
    }
    __syncthreads();

    if (DO_GEMM) {
        // H = relu(acc*dinv + b1) -> bf16 Hs[64][72]
        for (int i = t; i < 64 * 8; i += 256) {
            int d = i >> 3, s2 = i & 7;
            float dd = (d < nlocal) ? dinv[node0 + d] : 0.f;
            float4 ba = *(const float4*)(bias + s2 * 8);
            float4 bb = *(const float4*)(bias + s2 * 8 + 4);
            float h0 = fmaxf(fmaf(acc[(s2 * 8 + 0) * 65 + d], dd, ba.x), 0.f);
            float h1 = fmaxf(fmaf(acc[(s2 * 8 + 1) * 65 + d], dd, ba.y), 0.f);
            float h2 = fmaxf(fmaf(acc[(s2 * 8 + 2) * 65 + d], dd, ba.z), 0.f);
            float h3 = fmaxf(fmaf(acc[(s2 * 8 + 3) * 65 + d], dd, ba.w), 0.f);
            float h4 = fmaxf(fmaf(acc[(s2 * 8 + 4) * 65 + d], dd, bb.x), 0.f);
            float h5 = fmaxf(fmaf(acc[(s2 * 8 + 5) * 65 + d], dd, bb.y), 0.f);
            float h6 = fmaxf(fmaf(acc[(s2 * 8 + 6) * 65 + d], dd, bb.z), 0.f);
            float h7 = fmaxf(fmaf(acc[(s2 * 8 + 7) * 65 + d], dd, bb.w), 0.f);
            uint4 p;
            p.x = pack2(h0, h1); p.y = pack2(h2, h3);
            p.z = pack2(h4, h5); p.w = pack2(h6, h7);
            *(uint4*)(&Hs[d * 72 + s2 * 8]) = p;
        }
        __syncthreads();
        // H[64][64] @ W2[64][64] -> C, standard 64-row tile (4 waves x 4 n-tiles)
        int lane = t & 63;
        int w = t >> 6;
        int m = lane & 15;
        int q = lane >> 4;
        f32x4 c4[4];
#pragma unroll
        for (int nt = 0; nt < 4; ++nt) c4[nt] = (f32x4){0.f, 0.f, 0.f, 0.f};
#pragma unroll
        for (int s = 0; s < 2; ++s) {
            bf16x8 a = *(const bf16x8*)(&Hs[(16 * w + m) * 72 + s * 32 + q * 8]);
#pragma unroll
            for (int nt = 0; nt < 4; ++nt) {
                bf16x8 bb = *(const bf16x8*)(&W2s[(16 * nt + m) * 72 + s * 32 + q * 8]);
                c4[nt] = __builtin_amdgcn_mfma_f32_16x16x32_bf16(a, bb, c4[nt], 0, 0, 0);
            }
        }
        // acc region is dead -> reuse as bf16 C tile (alignment: 144B rows)
        unsigned short* Cs = (unsigned short*)acc;
#pragma unroll
        for (int nt = 0; nt < 4; ++nt)
#pragma unroll
            for (int r = 0; r < 4; ++r) {
                int row = 16 * w + q * 4 + r;
                int gn = node0 + row;
                float dd = (gn < N) ? dinv[gn] : 0.f;
                Cs[row * 72 + nt * 16 + m] = f2bf(c4[nt][r] * dd);
            }
        __syncthreads();
        unsigned short* outb = (unsigned short*)outv;
        for (int i = t; i < 64 * 8; i += 256) {
            int r = i >> 3, c8 = i & 7;
            int gn = node0 + r;
            if (gn < N)
                *(uint4*)(outb + (size_t)gn * 64 + c8 * 8) = *(const uint4*)(&Cs[r * 72 + c8 * 8]);
        }
    } else {
        float* outf = (float*)outv;
        for (int i = t; i < 64 * 8; i += 256) {
            int d = i >> 3, s2 = i & 7;
            int gn = node0 + d;
            if (gn >= N) continue;
            float dd = dinv[gn];
            float4 ba = *(const float4*)(bias + s2 * 8);
            float4 bb = *(const float4*)(bias + s2 * 8 + 4);
            float o0 = fmaf(acc[(s2 * 8 + 0) * 65 + d], dd, ba.x);
            float o1 = fmaf(acc[(s2 * 8 + 1) * 65 + d], dd, ba.y);
            float o2 = fmaf(acc[(s2 * 8 + 2) * 65 + d], dd, ba.z);
            float o3 = fmaf(acc[(s2 * 8 + 3) * 65 + d], dd, ba.w);
            float o4 = fmaf(acc[(s2 * 8 + 4) * 65 + d], dd, bb.x);
            float o5 = fmaf(acc[(s2 * 8 + 5) * 65 + d], dd, bb.y);
            float o6 = fmaf(acc[(s2 * 8 + 6) * 65 + d], dd, bb.z);
            float o7 = fmaf(acc[(s2 * 8 + 7) * 65 + d], dd, bb.w);
            float* op = outf + (size_t)gn * 64 + s2 * 8;
            *(float4*)(op)     = make_float4(o0, o1, o2, o3);
            *(float4*)(op + 4) = make_float4(o4, o5, o6, o7);
        }
    }
}

// ---------------- launch ----------------
extern "C" void kernel_launch(void* const* d_in, const int* in_sizes, int n_in,
                              void* d_out, int out_size, void* d_ws, size_t ws_size,
                              hipStream_t stream) {
    const float* x  = (const float*)d_in[0];
    const int*   ei = (const int*)d_in[1];   // [2, E] int32
    const float* W1 = (const float*)d_in[2];
    const float* b1 = (const float*)d_in[3];
    const float* W2 = (const float*)d_in[4];
    const float* b2 = (const float*)d_in[5];

    const int N = in_sizes[0] / 128;  // 100000
    const int E = in_sizes[1] / 2;    // 3200000
    const int* src = ei;
    const int* dst = ei + E;
    float* out = (float*)d_out;

    const int nb   = (N + 63) >> BSHIFT;   // 1563
    const int nblk = (E + CH - 1) / CH;    // 391

    char* ws = (char*)d_ws;
    size_t off = 0;
    auto alloc = [&](size_t bytes) -> char* {
        char* p = ws + off;
        off = (off + bytes + 255) & ~(size_t)255;
        return p;
    };
    // persistent
    int*   packed      = (int*)alloc((size_t)E * 4);       // read by bdeg+both aggs
    float* dinv        = (float*)alloc((size_t)N * 4);
    int*   bucketbase  = (int*)alloc((size_t)(nb + 1) * 4);
    int*   buckettotal = (int*)alloc((size_t)nb * 4);
    unsigned short* W1t = (unsigned short*)alloc(64 * 128 * 2);
    unsigned short* W2t = (unsigned short*)alloc(64 * 64 * 2);
    unsigned short* bufA = (unsigned short*)alloc((size_t)N * 64 * 2);  // bf16 (xW1)*dinv
    unsigned short* bufB = (unsigned short*)alloc((size_t)N * 64 * 2);  // bf16 (hW2)*dinv
    // histmat (nblk*nb*4 ~ 2.44 MB) aliases bufA: last read (bscatter)
    // strictly precedes gemm1's bufA writes.
    int* histmat = (int*)bufA;

    hist_kernel<<<nblk + 48, 256, 0, stream>>>(dst, histmat, E, nb, nblk, W1, W2, W1t, W2t);
    scancol_kernel<<<nb, 256, 0, stream>>>(histmat, histmat, buckettotal, nb, nblk);
    scanbucket_kernel<<<1, 256, 0, stream>>>(buckettotal, bucketbase, nb, E);
    bscatter_kernel<<<nblk, 256, 0, stream>>>(src, dst, histmat, bucketbase, packed, E, nb);
    bdeg_kernel<<<nb, 256, 0, stream>>>(packed, bucketbase, dinv, N);

    gemm1_kernel<<<(N + 63) / 64, 256, 0, stream>>>(x, W1t, dinv, bufA, N);
    agg_bucket_kernel<true><<<nb, 256, 0, stream>>>(
        (const unsigned*)bufA, packed, bucketbase, dinv, b1, W2t, bufB, N);
    agg_bucket_kernel<false><<<nb, 256, 0, stream>>>(
        (const unsigned*)bufB, packed, bucketbase, dinv, b2, W2t, out, N);
}

// Round 10
// 319.556 us; speedup vs baseline: 7.9268x; 7.9268x over previous
//
#include <hip/hip_runtime.h>
#include <cstdint>

// ===================== GCN encoder on MI355X =====================
// out = gcn(relu(gcn(x, W1, b1)), W2, b2)
// gcn(x,W,b)[i] = dinv[i] * ( sum_{e: dst=i} (xW*dinv)[src] + (xW*dinv)[i] ) + b
// dinv = rsqrt(indeg+1) (self-loop), identical for both layers.
//
// R16 = revert to R14 (best verified structure). R15's LDS-fp32-atomic
// aggregate was 20x slower (205M ds atomics, same-address serialization,
// VALUBusy 0.9%): the bcsr CSR sort is cheap by comparison. Final ledger:
//  - aggregate gather floor ~59us x2 (R6-R9: locality sort, NT hints,
//    degree sort, load batching all within 1% -- L2-miss-path latency on
//    a 12.8MB table straddling 8x4MiB XCD L2s).
//  - agg1 fuses gemm2 per-wave (saves gemm2 dispatch + 25.6MB round-trip;
//    epilogue costs ~9.5us in-kernel -> net ~ -3us vs split).
//  - build: hist/scancol/bscatter/bcsr with in-block scanbucket; CH=8192.
//    Global-atomic deg (R13, +110us) and sort-removal (R15, +2200us)
//    both catastrophically refuted.

#define BSHIFT 7          // 128 nodes per bucket
#define NBMAX 784         // >= ceil(100000/128) = 782
#define CH 8192           // edges per block in passes A/C
#define MAXB 6016         // LDS-cached bucket capacity (avg 4092, +30 sigma)

typedef __attribute__((ext_vector_type(8))) short bf16x8;
typedef __attribute__((ext_vector_type(4))) float f32x4;

union U8 { unsigned u[4]; bf16x8 v; };

// ---------------- bf16 helpers ----------------
__device__ inline unsigned short f2bf(float f) {
    unsigned u = __float_as_uint(f);
    unsigned r = (u + 0x7FFFu + ((u >> 16) & 1u)) >> 16;  // RNE
    return (unsigned short)r;
}
__device__ inline unsigned pack2(float a, float b) {
    return (unsigned)f2bf(a) | ((unsigned)f2bf(b) << 16);
}
__device__ inline float blo(unsigned u) { return __uint_as_float(u << 16); }
__device__ inline float bhi(unsigned u) { return __uint_as_float(u & 0xFFFF0000u); }

// ---------------- pass A: bucket histogram (+ folded weight prep) ----------
__global__ __launch_bounds__(256) void hist_kernel(const int* __restrict__ dst,
                                                   int* __restrict__ histmat,
                                                   int E, int nb, int nblk,
                                                   const float* __restrict__ W1,
                                                   const float* __restrict__ W2,
                                                   unsigned short* __restrict__ W1t,
                                                   unsigned short* __restrict__ W2t) {
    if (blockIdx.x >= (unsigned)nblk) {
        // weight-prep blocks: W[K][64] fp32 -> Wt[64][K] bf16
        int i = (blockIdx.x - nblk) * 256 + threadIdx.x;
        if (i < 128 * 64) {
            int k = i >> 6, n = i & 63;
            W1t[n * 128 + k] = f2bf(W1[i]);
        }
        int j = i - 128 * 64;
        if (j >= 0 && j < 64 * 64) {
            int k = j >> 6, n = j & 63;
            W2t[n * 64 + k] = f2bf(W2[j]);
        }
        return;
    }
    __shared__ int hist[NBMAX];
    int t = threadIdx.x;
    for (int b = t; b < nb; b += 256) hist[b] = 0;
    __syncthreads();
    int base = blockIdx.x * CH;
#pragma unroll
    for (int j = 0; j < CH / 1024; ++j) {
        int idx = base + j * 1024 + t * 4;
        if (idx + 4 <= E) {
            int4 d = *(const int4*)(dst + idx);
            atomicAdd(&hist[d.x >> BSHIFT], 1);
            atomicAdd(&hist[d.y >> BSHIFT], 1);
            atomicAdd(&hist[d.z >> BSHIFT], 1);
            atomicAdd(&hist[d.w >> BSHIFT], 1);
        } else {
            for (int k = 0; k < 4; ++k)
                if (idx + k < E) atomicAdd(&hist[dst[idx + k] >> BSHIFT], 1);
        }
    }
    __syncthreads();
    for (int b = t; b < nb; b += 256) histmat[blockIdx.x * nb + b] = hist[b];
}

// ---------------- pass B: per-bucket scan over blocks (nblk <= 1024) --------
__global__ __launch_bounds__(256) void scancol_kernel(const int* __restrict__ histmat,
                                                      int* __restrict__ colbase,
                                                      int* __restrict__ buckettotal,
                                                      int nb, int nblk) {
    __shared__ int ts[256];
    int b = blockIdx.x;
    int t = threadIdx.x;
    int v[4];
    int tsum = 0;
#pragma unroll
    for (int k = 0; k < 4; ++k) {
        int blk = t * 4 + k;
        v[k] = (blk < nblk) ? histmat[blk * nb + b] : 0;
        tsum += v[k];
    }
    ts[t] = tsum;
    __syncthreads();
    for (int ofs = 1; ofs < 256; ofs <<= 1) {
        int val = (t >= ofs) ? ts[t - ofs] : 0;
        __syncthreads();
        ts[t] += val;
        __syncthreads();
    }
    int run = ts[t] - tsum;
#pragma unroll
    for (int k = 0; k < 4; ++k) {
        int blk = t * 4 + k;
        if (blk < nblk) colbase[blk * nb + b] = run;
        run += v[k];
    }
    if (t == 255) buckettotal[b] = ts[255];
}

// ---------------- pass C: scatter into bucket regions (LDS cursors) ---------
// bucketbase computed in-block from buckettotal (no scanbucket dispatch).
__global__ __launch_bounds__(256) void bscatter_kernel(const int* __restrict__ src,
                                                       const int* __restrict__ dst,
                                                       const int* __restrict__ colbase,
                                                       const int* __restrict__ buckettotal,
                                                       int* __restrict__ packed,
                                                       int E, int nb) {
    __shared__ int cur[NBMAX];
    __shared__ int ts2[256];
    int t = threadIdx.x;
    int v4[4];
    int tsum = 0;
#pragma unroll
    for (int k = 0; k < 4; ++k) {
        int bb = t * 4 + k;
        v4[k] = (bb < nb) ? buckettotal[bb] : 0;
        tsum += v4[k];
    }
    ts2[t] = tsum;
    __syncthreads();
    for (int ofs = 1; ofs < 256; ofs <<= 1) {
        int val = (t >= ofs) ? ts2[t - ofs] : 0;
        __syncthreads();
        ts2[t] += val;
        __syncthreads();
    }
    int run = ts2[t] - tsum;
#pragma unroll
    for (int k = 0; k < 4; ++k) {
        int bb = t * 4 + k;
        if (bb < nb) cur[bb] = run + colbase[blockIdx.x * nb + bb];
        run += v4[k];
    }
    __syncthreads();
    int base = blockIdx.x * CH;
#pragma unroll
    for (int j = 0; j < CH / 1024; ++j) {
        int idx = base + j * 1024 + t * 4;
        if (idx + 4 <= E) {
            int4 d = *(const int4*)(dst + idx);
            int4 s = *(const int4*)(src + idx);
            int p;
            p = atomicAdd(&cur[d.x >> BSHIFT], 1); packed[p] = ((d.x & 127) << 17) | s.x;
            p = atomicAdd(&cur[d.y >> BSHIFT], 1); packed[p] = ((d.y & 127) << 17) | s.y;
            p = atomicAdd(&cur[d.z >> BSHIFT], 1); packed[p] = ((d.z & 127) << 17) | s.z;
            p = atomicAdd(&cur[d.w >> BSHIFT], 1); packed[p] = ((d.w & 127) << 17) | s.w;
        } else {
            for (int k = 0; k < 4; ++k)
                if (idx + k < E) {
                    int dd = dst[idx + k], ss = src[idx + k];
                    int p = atomicAdd(&cur[dd >> BSHIFT], 1);
                    packed[p] = ((dd & 127) << 17) | ss;
                }
        }
    }
}

// ---------------- pass D: within-bucket CSR + rowptr + dinv (LDS-cached) ----
__global__ __launch_bounds__(256) void bcsr_kernel(const int* __restrict__ packed,
                                                   const int* __restrict__ buckettotal,
                                                   int* __restrict__ rowptr,
                                                   float* __restrict__ dinv,
                                                   int* __restrict__ csr,
                                                   int N, int nb) {
    __shared__ int deg[128];
    __shared__ int lrp[128];
    __shared__ int ts[128];
    __shared__ int ts2[256];
    __shared__ int shbb[2];
    __shared__ int ebuf[MAXB];
    __shared__ int obuf[MAXB];
    int b = blockIdx.x;
    int t = threadIdx.x;
    if (t < 128) deg[t] = 0;
    // in-block scan of buckettotal -> [bb0, bb1)
    int v4[4];
    int tsum = 0;
#pragma unroll
    for (int k = 0; k < 4; ++k) {
        int bb = t * 4 + k;
        v4[k] = (bb < nb) ? buckettotal[bb] : 0;
        tsum += v4[k];
    }
    ts2[t] = tsum;
    __syncthreads();
    for (int ofs = 1; ofs < 256; ofs <<= 1) {
        int val = (t >= ofs) ? ts2[t - ofs] : 0;
        __syncthreads();
        ts2[t] += val;
        __syncthreads();
    }
    int run = ts2[t] - tsum;
#pragma unroll
    for (int k = 0; k < 4; ++k) {
        int bb = t * 4 + k;
        if (bb == b) { shbb[0] = run; shbb[1] = run + v4[k]; }
        run += v4[k];
    }
    __syncthreads();
    int bb0 = shbb[0];
    int bb1 = shbb[1];
    int cnt = bb1 - bb0;
    bool fits = (cnt <= MAXB);
    if (fits) {
        for (int i = t; i < cnt; i += 256) {
            int v = packed[bb0 + i];
            ebuf[i] = v;
            atomicAdd(&deg[v >> 17], 1);
        }
    } else {
        for (int i = t; i < cnt; i += 256)
            atomicAdd(&deg[packed[bb0 + i] >> 17], 1);
    }
    __syncthreads();
    if (t < 128) ts[t] = deg[t];
    __syncthreads();
    for (int ofs = 1; ofs < 128; ofs <<= 1) {
        int v = (t < 128 && t >= ofs) ? ts[t - ofs] : 0;
        __syncthreads();
        if (t < 128) ts[t] += v;
        __syncthreads();
    }
    int node0 = b << BSHIFT;
    int nlocal = min(128, N - node0);
    if (t < 128) lrp[t] = ts[t] - deg[t];
    if (t < nlocal) {
        rowptr[node0 + t] = bb0 + (ts[t] - deg[t]);
        dinv[node0 + t] = rsqrtf((float)(deg[t] + 1));
    }
    if (t == nlocal) rowptr[node0 + nlocal] = bb1;
    __syncthreads();
    if (fits) {
        for (int i = t; i < cnt; i += 256) {
            int v = ebuf[i];
            int p = atomicAdd(&lrp[v >> 17], 1);
            obuf[p] = v & 0x1FFFF;
        }
        __syncthreads();
        for (int i = t; i < cnt; i += 256) csr[bb0 + i] = obuf[i];  // coalesced
    } else {
        for (int i = t; i < cnt; i += 256) {
            int v = packed[bb0 + i];
            int p = atomicAdd(&lrp[v >> 17], 1);
            csr[bb0 + p] = v & 0x1FFFF;
        }
    }
}

// ------- MFMA GEMM1: bufA[M,64]bf16 = (X[M,128]f32 @ W1[128,64]) * dinv ----
__global__ __launch_bounds__(256) void gemm1_kernel(const float* __restrict__ X,
                                                    const unsigned short* __restrict__ Wt,
                                                    const float* __restrict__ dinv,
                                                    unsigned short* __restrict__ Ybf, int M) {
    constexpr int K = 128, KP = 136;
    __shared__ unsigned short Xs[64 * KP];   // reused as Cs (64*72) in epilogue
    __shared__ unsigned short Ws[64 * KP];
    int t = threadIdx.x;
    int row0 = blockIdx.x * 64;

    for (int i = t; i < 64 * K / 8; i += 256) {
        int r = i / (K / 8), c8 = i % (K / 8);
        *(uint4*)(&Ws[r * KP + c8 * 8]) = ((const uint4*)Wt)[i];
    }
    for (int i = t; i < 64 * K / 4; i += 256) {
        int r = i / (K / 4), c4 = i % (K / 4);
        int gr = row0 + r;
        float4 v = make_float4(0.f, 0.f, 0.f, 0.f);
        if (gr < M) v = ((const float4*)(X + (size_t)gr * K))[c4];
        uint2 p;
        p.x = pack2(v.x, v.y);
        p.y = pack2(v.z, v.w);
        *(uint2*)(&Xs[r * KP + c4 * 4]) = p;
    }
    __syncthreads();

    int lane = t & 63;
    int w = t >> 6;
    int m = lane & 15;
    int q = lane >> 4;

    f32x4 acc[4];
#pragma unroll
    for (int nt = 0; nt < 4; ++nt) acc[nt] = (f32x4){0.f, 0.f, 0.f, 0.f};

#pragma unroll
    for (int s = 0; s < K / 32; ++s) {
        bf16x8 a = *(const bf16x8*)(&Xs[(16 * w + m) * KP + s * 32 + q * 8]);
#pragma unroll
        for (int nt = 0; nt < 4; ++nt) {
            bf16x8 b = *(const bf16x8*)(&Ws[(16 * nt + m) * KP + s * 32 + q * 8]);
            acc[nt] = __builtin_amdgcn_mfma_f32_16x16x32_bf16(a, b, acc[nt], 0, 0, 0);
        }
    }
    __syncthreads();

    unsigned short* Cs = Xs;
#pragma unroll
    for (int nt = 0; nt < 4; ++nt)
#pragma unroll
        for (int r = 0; r < 4; ++r) {
            int row = 16 * w + q * 4 + r;
            int gr = row0 + row;
            float d = (gr < M) ? dinv[gr] : 0.f;
            Cs[row * 72 + nt * 16 + m] = f2bf(acc[nt][r] * d);
        }
    __syncthreads();
    for (int i = t; i < 64 * 64 / 8; i += 256) {
        int r = i >> 3, c8 = i & 7;
        int gr = row0 + r;
        if (gr < M)
            *(uint4*)(Ybf + (size_t)gr * 64 + c8 * 8) = *(const uint4*)(&Cs[r * 72 + c8 * 8]);
    }
}

// ---------------- aggregation kernels ----------------
#define ACC8(v)                                      \
    acc[0] += blo(v.x); acc[1] += bhi(v.x);          \
    acc[2] += blo(v.y); acc[3] += bhi(v.y);          \
    acc[4] += blo(v.z); acc[5] += bhi(v.z);          \
    acc[6] += blo(v.w); acc[7] += bhi(v.w);

#define GATHER_BODY                                                     \
    {                                                                   \
        uint4 v = *(const uint4*)(hsu + (size_t)node * 32 + sub * 4);   \
        acc[0] = blo(v.x); acc[1] = bhi(v.x);                           \
        acc[2] = blo(v.y); acc[3] = bhi(v.y);                           \
        acc[4] = blo(v.z); acc[5] = bhi(v.z);                           \
        acc[6] = blo(v.w); acc[7] = bhi(v.w);                           \
    }                                                                   \
    int e0 = rowptr[node];                                              \
    int e1 = rowptr[node + 1];                                          \
    int e = e0;                                                         \
    for (; e + 8 <= e1; e += 8) {                                       \
        int idx = csr[e + sub];                                         \
        int s0 = __shfl(idx, gbase + 0, 64);                            \
        int s1 = __shfl(idx, gbase + 1, 64);                            \
        int s2 = __shfl(idx, gbase + 2, 64);                            \
        int s3 = __shfl(idx, gbase + 3, 64);                            \
        int s4 = __shfl(idx, gbase + 4, 64);                            \
        int s5 = __shfl(idx, gbase + 5, 64);                            \
        int s6 = __shfl(idx, gbase + 6, 64);                            \
        int s7 = __shfl(idx, gbase + 7, 64);                            \
        uint4 v0 = *(const uint4*)(hsu + (size_t)s0 * 32 + sub * 4);    \
        uint4 v1 = *(const uint4*)(hsu + (size_t)s1 * 32 + sub * 4);    \
        uint4 v2 = *(const uint4*)(hsu + (size_t)s2 * 32 + sub * 4);    \
        uint4 v3 = *(const uint4*)(hsu + (size_t)s3 * 32 + sub * 4);    \
        uint4 v4 = *(const uint4*)(hsu + (size_t)s4 * 32 + sub * 4);    \
        uint4 v5 = *(const uint4*)(hsu + (size_t)s5 * 32 + sub * 4);    \
        uint4 v6 = *(const uint4*)(hsu + (size_t)s6 * 32 + sub * 4);    \
        uint4 v7 = *(const uint4*)(hsu + (size_t)s7 * 32 + sub * 4);    \
        ACC8(v0); ACC8(v1); ACC8(v2); ACC8(v3);                         \
        ACC8(v4); ACC8(v5); ACC8(v6); ACC8(v7);                         \
    }                                                                   \
    for (; e < e1; ++e) {                                               \
        int s = csr[e];                                                 \
        uint4 v = *(const uint4*)(hsu + (size_t)s * 32 + sub * 4);      \
        ACC8(v);                                                        \
    }

// layer 1: gather -> relu(agg*dinv+b1) -> per-wave MFMA (@W2) -> *dinv -> bufB
__global__ __launch_bounds__(256) void aggregate_gemm_kernel(
        const unsigned* __restrict__ hsu, const int* __restrict__ rowptr,
        const int* __restrict__ csr, const float* __restrict__ dinv,
        const float* __restrict__ bias, const unsigned short* __restrict__ W2t,
        unsigned short* __restrict__ outb, int N) {
    __shared__ unsigned short W2s[64 * 72];   // 9216 B
    __shared__ unsigned short Cs[4][8 * 72];  // 4608 B, wave-private patches
    int t = threadIdx.x;
    // stage W2 (single barrier, BEFORE the divergent-length gather)
    for (int i = t; i < 64 * 64 / 8; i += 256) {
        int r = i >> 3, c8 = i & 7;
        *(uint4*)(&W2s[r * 72 + c8 * 8]) = ((const uint4*)W2t)[i];
    }
    __syncthreads();

    int node0 = blockIdx.x * 32;
    int node = node0 + (t >> 3);
    int sub = t & 7;
    int gbase = t & 56;

    float acc[8] = {0.f, 0.f, 0.f, 0.f, 0.f, 0.f, 0.f, 0.f};
    uint4 pk = make_uint4(0u, 0u, 0u, 0u);
    if (node < N) {
        GATHER_BODY
        float d = dinv[node];
        float4 b0 = *(const float4*)(bias + sub * 8);
        float4 b1 = *(const float4*)(bias + sub * 8 + 4);
        float o0 = fmaxf(fmaf(acc[0], d, b0.x), 0.f);
        float o1 = fmaxf(fmaf(acc[1], d, b0.y), 0.f);
        float o2 = fmaxf(fmaf(acc[2], d, b0.z), 0.f);
        float o3 = fmaxf(fmaf(acc[3], d, b0.w), 0.f);
        float o4 = fmaxf(fmaf(acc[4], d, b1.x), 0.f);
        float o5 = fmaxf(fmaf(acc[5], d, b1.y), 0.f);
        float o6 = fmaxf(fmaf(acc[6], d, b1.z), 0.f);
        float o7 = fmaxf(fmaf(acc[7], d, b1.w), 0.f);
        pk.x = pack2(o0, o1); pk.y = pack2(o2, o3);
        pk.z = pack2(o4, o5); pk.w = pack2(o6, o7);
    }

    // per-wave MFMA: A[16][64], rows 0-7 = this wave's 8 nodes (rows 8-15 = 0).
    // Shfls with FULL exec (convergent); select after (divergent shfl = UB).
    int lane = t & 63;
    int m16 = lane & 15;
    int q = lane >> 4;
    int wv = t >> 6;
    int wnode0 = node0 + wv * 8;
    bool am = (m16 < 8);
    int sl0 = ((m16 & 7) << 3) + q;       // src lane for s=0 frag
    int sl1 = sl0 + 4;                    // src lane for s=1 frag
    unsigned a00 = (unsigned)__shfl((int)pk.x, sl0, 64);
    unsigned a01 = (unsigned)__shfl((int)pk.y, sl0, 64);
    unsigned a02 = (unsigned)__shfl((int)pk.z, sl0, 64);
    unsigned a03 = (unsigned)__shfl((int)pk.w, sl0, 64);
    unsigned a10 = (unsigned)__shfl((int)pk.x, sl1, 64);
    unsigned a11 = (unsigned)__shfl((int)pk.y, sl1, 64);
    unsigned a12 = (unsigned)__shfl((int)pk.z, sl1, 64);
    unsigned a13 = (unsigned)__shfl((int)pk.w, sl1, 64);
    U8 fa0, fa1;
    fa0.u[0] = am ? a00 : 0u;
    fa0.u[1] = am ? a01 : 0u;
    fa0.u[2] = am ? a02 : 0u;
    fa0.u[3] = am ? a03 : 0u;
    fa1.u[0] = am ? a10 : 0u;
    fa1.u[1] = am ? a11 : 0u;
    fa1.u[2] = am ? a12 : 0u;
    fa1.u[3] = am ? a13 : 0u;

    unsigned short* Cw = &Cs[wv][0];
#pragma unroll
    for (int nt = 0; nt < 4; ++nt) {
        bf16x8 bb0 = *(const bf16x8*)(&W2s[(nt * 16 + m16) * 72 + q * 8]);
        bf16x8 bb1 = *(const bf16x8*)(&W2s[(nt * 16 + m16) * 72 + 32 + q * 8]);
        f32x4 c4 = (f32x4){0.f, 0.f, 0.f, 0.f};
        c4 = __builtin_amdgcn_mfma_f32_16x16x32_bf16(fa0.v, bb0, c4, 0, 0, 0);
        c4 = __builtin_amdgcn_mfma_f32_16x16x32_bf16(fa1.v, bb1, c4, 0, 0, 0);
        if (q < 2) {
#pragma unroll
            for (int r = 0; r < 4; ++r) {
                int row = q * 4 + r;       // 0..7 -> this wave's node row
                int gn = wnode0 + row;
                float dd = (gn < N) ? dinv[gn] : 0.f;
                Cw[row * 72 + nt * 16 + m16] = f2bf(c4[r] * dd);
            }
        }
    }
    // wave-private LDS readback (no cross-wave hazard -> no barrier needed)
    int row = lane >> 3, c8 = lane & 7;
    int gn = wnode0 + row;
    if (gn < N)
        *(uint4*)(outb + (size_t)gn * 64 + c8 * 8) = *(const uint4*)(&Cw[row * 72 + c8 * 8]);
}

// layer 2: gather -> agg*dinv + b2 -> fp32 out
__global__ __launch_bounds__(256) void aggregate_out_kernel(
        const unsigned* __restrict__ hsu, const int* __restrict__ rowptr,
        const int* __restrict__ csr, const float* __restrict__ dinv,
        const float* __restrict__ bias, float* __restrict__ outv, int N) {
    int t = threadIdx.x;
    int node = blockIdx.x * 32 + (t >> 3);
    if (node >= N) return;
    int sub = t & 7;
    int gbase = t & 56;
    float acc[8];
    GATHER_BODY
    float d = dinv[node];
    float4 b0 = *(const float4*)(bias + sub * 8);
    float4 b1 = *(const float4*)(bias + sub * 8 + 4);
    float o[8];
    o[0] = fmaf(acc[0], d, b0.x); o[1] = fmaf(acc[1], d, b0.y);
    o[2] = fmaf(acc[2], d, b0.z); o[3] = fmaf(acc[3], d, b0.w);
    o[4] = fmaf(acc[4], d, b1.x); o[5] = fmaf(acc[5], d, b1.y);
    o[6] = fmaf(acc[6], d, b1.z); o[7] = fmaf(acc[7], d, b1.w);
    float* op = outv + (size_t)node * 64 + sub * 8;
    *(float4*)(op)     = make_float4(o[0], o[1], o[2], o[3]);
    *(float4*)(op + 4) = make_float4(o[4], o[5], o[6], o[7]);
}

// ---------------- launch ----------------
extern "C" void kernel_launch(void* const* d_in, const int* in_sizes, int n_in,
                              void* d_out, int out_size, void* d_ws, size_t ws_size,
                              hipStream_t stream) {
    const float* x  = (const float*)d_in[0];
    const int*   ei = (const int*)d_in[1];   // [2, E] int32
    const float* W1 = (const float*)d_in[2];
    const float* b1 = (const float*)d_in[3];
    const float* W2 = (const float*)d_in[4];
    const float* b2 = (const float*)d_in[5];

    const int N = in_sizes[0] / 128;  // 100000
    const int E = in_sizes[1] / 2;    // 3200000
    const int* src = ei;
    const int* dst = ei + E;
    float* out = (float*)d_out;

    const int nb   = (N + 127) >> BSHIFT;  // 782
    const int nblk = (E + CH - 1) / CH;    // 391

    char* ws = (char*)d_ws;
    size_t off = 0;
    auto alloc = [&](size_t bytes) -> char* {
        char* p = ws + off;
        off = (off + bytes + 255) & ~(size_t)255;
        return p;
    };
    // persistent
    int*   csr         = (int*)alloc((size_t)E * 4);
    int*   rowptr      = (int*)alloc((size_t)(N + 1) * 4);
    float* dinv        = (float*)alloc((size_t)N * 4);
    int*   buckettotal = (int*)alloc((size_t)nb * 4);
    unsigned short* W1t = (unsigned short*)alloc(64 * 128 * 2);
    unsigned short* W2t = (unsigned short*)alloc(64 * 64 * 2);
    unsigned short* bufA = (unsigned short*)alloc((size_t)N * 64 * 2);  // bf16 (xW1)*dinv
    unsigned short* bufB = (unsigned short*)alloc((size_t)N * 64 * 2);  // bf16 (hW2)*dinv
    // aliases:
    //  - histmat (nblk*nb*4 ~ 1.22 MB) in csr region: last read (bscatter)
    //    strictly precedes bcsr's csr writes.
    //  - packed aliases bufB: consumed by bcsr BEFORE agg1 writes bufB;
    //    gemm1 (writes bufA) runs after bcsr, no overlap with packed.
    int* histmat = csr;
    int* packed  = (int*)bufB;  // E*4 = 12.8 MB == N*64*2

    hist_kernel<<<nblk + 48, 256, 0, stream>>>(dst, histmat, E, nb, nblk, W1, W2, W1t, W2t);
    scancol_kernel<<<nb, 256, 0, stream>>>(histmat, histmat, buckettotal, nb, nblk);
    bscatter_kernel<<<nblk, 256, 0, stream>>>(src, dst, histmat, buckettotal, packed, E, nb);
    bcsr_kernel<<<nb, 256, 0, stream>>>(packed, buckettotal, rowptr, dinv, csr, N, nb);

    gemm1_kernel<<<(N + 63) / 64, 256, 0, stream>>>(x, W1t, dinv, bufA, N);
    aggregate_gemm_kernel<<<(N + 31) / 32, 256, 0, stream>>>(
        (const unsigned*)bufA, rowptr, csr, dinv, b1, W2t, bufB, N);
    aggregate_out_kernel<<<(N + 31) / 32, 256, 0, stream>>>(
        (const unsigned*)bufB, rowptr, csr, dinv, b2, out, N);
}